// Round 1
// baseline (459.508 us; speedup 1.0000x reference)
//
#include <hip/hip_runtime.h>
#include <stdint.h>

typedef __attribute__((ext_vector_type(8))) short short8;   // 8 bf16 in 4 VGPRs (MFMA A/B frag)
typedef __attribute__((ext_vector_type(4))) float f32x4;    // MFMA C/D frag

__device__ __forceinline__ unsigned short f2bf(float f) {
    unsigned int u = __float_as_uint(f);
    u = (u + 0x7FFFu + ((u >> 16) & 1u)) >> 16;  // RNE
    return (unsigned short)u;
}
__device__ __forceinline__ float bf2f(unsigned short h) {
    return __uint_as_float(((unsigned int)h) << 16);
}

// ---------------------------------------------------------------------------
// Pack W -> transposed bf16 hi/lo: Wt[col][i], col in [0,1664)
//   col < 1600: W[k=col>>6][i][o=col&63];  col >= 1600: root[i][col-1600]
// Split-W error feedback: Whi = bf16(w), Wlo = bf16(w - f32(Whi))
// ---------------------------------------------------------------------------
template<int KIN>
__global__ void pack_w_kernel(const float* __restrict__ W, const float* __restrict__ root,
                              unsigned short* __restrict__ Wh, unsigned short* __restrict__ Wl) {
    int t = blockIdx.x * 256 + threadIdx.x;
    if (t >= 1664 * KIN) return;
    int c = t / KIN, i = t % KIN;
    float v = (c < 1600) ? W[((size_t)(c >> 6) * KIN + i) * 64 + (c & 63)]
                         : root[(size_t)i * 64 + (c - 1600)];
    unsigned short h = f2bf(v);
    Wh[t] = h;
    Wl[t] = f2bf(v - bf2f(h));
}

// ---------------------------------------------------------------------------
// float -> bf16 convert (optional ReLU) for the GEMM A operand
// ---------------------------------------------------------------------------
template<bool RELU>
__global__ void conv_bf16_kernel(const float* __restrict__ in, unsigned short* __restrict__ out, int n) {
    int t = blockIdx.x * 256 + threadIdx.x;
    if (t >= n) return;
    float v = in[t];
    if (RELU) v = fmaxf(v, 0.f);
    out[t] = f2bf(v);
}

// ---------------------------------------------------------------------------
// y[n, col] = Xb[n,:] @ (Whi+Wlo)[:, col] for col<1600 ; agg[n,o]=...+bias for col>=1600
// Block = 4 waves; wave handles a 16-row strip x 128 cols (8 MFMA col-tiles).
// No LDS: A frag is one coalesced 16B/lane load (16xK row block is contiguous);
// B frags stream from transposed pack (L1/L2-resident, 32KB per block).
// mfma_f32_16x16x32_bf16 layouts: A[m=lane&15][k=8*(lane>>4)+j],
// B[k=8*(lane>>4)+j][n=lane&15], D col=lane&15, row=(lane>>4)*4+reg  [guide §3]
// ---------------------------------------------------------------------------
template<int KIN, typename YT>
__global__ __launch_bounds__(256) void gemm_mfma_kernel(
    const unsigned short* __restrict__ Xb,
    const unsigned short* __restrict__ Wh, const unsigned short* __restrict__ Wl,
    YT* __restrict__ y, float* __restrict__ agg, const float* __restrict__ bias, int N)
{
    constexpr int KCH = KIN / 32;
    const int lane = threadIdx.x & 63;
    const int wave = threadIdx.x >> 6;
    const int lrow = lane & 15;
    const int lch  = lane >> 4;
    const int nbase = blockIdx.x * 128;
    const int mrow  = blockIdx.y * 64 + wave * 16;

    short8 afrag[KCH];
    {
        int ar = mrow + lrow;
        if (ar > N - 1) ar = N - 1;           // clamp (values discarded by epilogue guard)
        const unsigned short* ap = Xb + (size_t)ar * KIN + lch * 8;
        #pragma unroll
        for (int kc = 0; kc < KCH; kc++)
            afrag[kc] = *reinterpret_cast<const short8*>(ap + kc * 32);
    }

    f32x4 acc[8];
    #pragma unroll
    for (int c = 0; c < 8; c++) acc[c] = (f32x4){0.f, 0.f, 0.f, 0.f};

    #pragma unroll
    for (int c = 0; c < 8; c++) {
        const size_t coff = (size_t)(nbase + c * 16 + lrow) * KIN + lch * 8;
        #pragma unroll
        for (int kc = 0; kc < KCH; kc++) {
            short8 bh = *reinterpret_cast<const short8*>(Wh + coff + kc * 32);
            short8 bl = *reinterpret_cast<const short8*>(Wl + coff + kc * 32);
            acc[c] = __builtin_amdgcn_mfma_f32_16x16x32_bf16(afrag[kc], bh, acc[c], 0, 0, 0);
            acc[c] = __builtin_amdgcn_mfma_f32_16x16x32_bf16(afrag[kc], bl, acc[c], 0, 0, 0);
        }
    }

    const int rb = mrow + lch * 4;  // D row base for this lane
    #pragma unroll
    for (int c = 0; c < 8; c++) {
        int colb = nbase + c * 16;
        int col  = colb + lrow;
        if (colb < 1600) {
            #pragma unroll
            for (int r = 0; r < 4; r++) {
                int m = rb + r;
                if (m < N) {
                    if constexpr (sizeof(YT) == 4) y[(size_t)m * 1600 + col] = acc[c][r];
                    else                           y[(size_t)m * 1600 + col] = f2bf(acc[c][r]);
                }
            }
        } else {
            int o = col - 1600;
            float bv = bias[o];
            #pragma unroll
            for (int r = 0; r < 4; r++) {
                int m = rb + r;
                if (m < N) agg[(size_t)m * 64 + o] = acc[c][r] + bv;
            }
        }
    }
}

// ---------------------------------------------------------------------------
// Per-edge gather + basis-weighted sum + atomic scatter.
// 1 wave per edge; lane = output channel (64). Gathers are contiguous 256B
// rows of y; one coalesced 256B atomicAdd row per edge into agg[dst].
// Spline basis (degree 1, dim 2, K=5) recomputed inline (cheap).
// ---------------------------------------------------------------------------
template<typename YT>
__global__ __launch_bounds__(256) void edge_kernel(
    const YT* __restrict__ y, float* __restrict__ agg,
    const int* __restrict__ src, const int* __restrict__ dst,
    const float* __restrict__ attr, int E)
{
    int e = blockIdx.x * 4 + (threadIdx.x >> 6);
    if (e >= E) return;
    int lane = threadIdx.x & 63;
    float2 av = reinterpret_cast<const float2*>(attr)[e];
    float v0 = av.x * 4.f, v1 = av.y * 4.f;
    float fl0 = floorf(v0), fl1 = floorf(v1);
    float f0 = v0 - fl0, f1 = v1 - fl1;
    int i0 = (int)fl0, i1 = (int)fl1;
    int s = src[e], d = dst[e];
    const YT* yb = y + (size_t)s * 1600 + lane;
    float msg = 0.f;
    #pragma unroll
    for (int t = 0; t < 4; t++) {
        int b0 = t & 1, b1 = t >> 1;
        float wx = b0 ? f0 : 1.f - f0;
        float wy = b1 ? f1 : 1.f - f1;
        int id0 = i0 + b0; if (id0 > 4) id0 = 4;
        int id1 = i1 + b1; if (id1 > 4) id1 = 4;
        float yv;
        if constexpr (sizeof(YT) == 4) yv = yb[(id0 + 5 * id1) * 64];
        else                           yv = bf2f(yb[(id0 + 5 * id1) * 64]);
        msg += wx * wy * yv;
    }
    atomicAdd(agg + (size_t)d * 64 + lane, msg);
}

// ---------------------------------------------------------------------------
// out[n,:3] = relu(agg2[n,:]) @ fc_w + fc_b   (wave per node, shuffle reduce)
// ---------------------------------------------------------------------------
__global__ __launch_bounds__(256) void final_kernel(
    const float* __restrict__ agg2, const float* __restrict__ fcw,
    const float* __restrict__ fcb, float* __restrict__ out, int N)
{
    int n = blockIdx.x * 4 + (threadIdx.x >> 6);
    if (n >= N) return;
    int lane = threadIdx.x & 63;
    float a = fmaxf(agg2[(size_t)n * 64 + lane], 0.f);
    float p0 = a * fcw[lane * 3 + 0];
    float p1 = a * fcw[lane * 3 + 1];
    float p2 = a * fcw[lane * 3 + 2];
    #pragma unroll
    for (int off = 32; off; off >>= 1) {
        p0 += __shfl_xor(p0, off);
        p1 += __shfl_xor(p1, off);
        p2 += __shfl_xor(p2, off);
    }
    if (lane == 0) {
        out[(size_t)n * 3 + 0] = p0 + fcb[0];
        out[(size_t)n * 3 + 1] = p1 + fcb[1];
        out[(size_t)n * 3 + 2] = p2 + fcb[2];
    }
}

// ---------------------------------------------------------------------------
extern "C" void kernel_launch(void* const* d_in, const int* in_sizes, int n_in,
                              void* d_out, int out_size, void* d_ws, size_t ws_size,
                              hipStream_t stream)
{
    const float* x     = (const float*)d_in[0];
    const int*   ei    = (const int*)  d_in[1];
    const float* attr  = (const float*)d_in[2];
    const float* W1    = (const float*)d_in[3];
    const float* root1 = (const float*)d_in[4];
    const float* b1    = (const float*)d_in[5];
    const float* W2    = (const float*)d_in[6];
    const float* root2 = (const float*)d_in[7];
    const float* b2    = (const float*)d_in[8];
    const float* fcw   = (const float*)d_in[9];
    const float* fcb   = (const float*)d_in[10];

    const int N = in_sizes[0] / 32;
    const int E = in_sizes[1] / 2;
    const int* srcp = ei;
    const int* dstp = ei + E;

    char* wsp = (char*)d_ws;
    auto alloc = [&](size_t bytes) -> char* {
        char* p = wsp;
        wsp += (bytes + 255) & ~(size_t)255;
        return p;
    };
    float*          agg1 = (float*)alloc((size_t)N * 64 * 4);
    float*          agg2 = (float*)alloc((size_t)N * 64 * 4);
    unsigned short* xb   = (unsigned short*)alloc((size_t)N * 32 * 2);
    unsigned short* h1b  = (unsigned short*)alloc((size_t)N * 64 * 2);
    unsigned short* w1h  = (unsigned short*)alloc((size_t)1664 * 32 * 2);
    unsigned short* w1l  = (unsigned short*)alloc((size_t)1664 * 32 * 2);
    unsigned short* w2h  = (unsigned short*)alloc((size_t)1664 * 64 * 2);
    unsigned short* w2l  = (unsigned short*)alloc((size_t)1664 * 64 * 2);
    void* ybuf = (void*)wsp;
    size_t used = (size_t)(wsp - (char*)d_ws);
    // fp32 y if workspace allows, else bf16 y (deterministic: ws_size fixed)
    bool y_f32 = (ws_size >= used + (size_t)N * 1600 * 4);

    const int Mtiles = (N + 63) / 64;
    dim3 ggrid(13, Mtiles);

    pack_w_kernel<32><<<(1664 * 32 + 255) / 256, 256, 0, stream>>>(W1, root1, w1h, w1l);
    pack_w_kernel<64><<<(1664 * 64 + 255) / 256, 256, 0, stream>>>(W2, root2, w2h, w2l);
    conv_bf16_kernel<false><<<(N * 32 + 255) / 256, 256, 0, stream>>>(x, xb, N * 32);

    if (y_f32) {
        float* y = (float*)ybuf;
        gemm_mfma_kernel<32, float><<<ggrid, 256, 0, stream>>>(xb, w1h, w1l, y, agg1, b1, N);
        edge_kernel<float><<<(E + 3) / 4, 256, 0, stream>>>(y, agg1, srcp, dstp, attr, E);
        conv_bf16_kernel<true><<<(N * 64 + 255) / 256, 256, 0, stream>>>(agg1, h1b, N * 64);
        gemm_mfma_kernel<64, float><<<ggrid, 256, 0, stream>>>(h1b, w2h, w2l, y, agg2, b2, N);
        edge_kernel<float><<<(E + 3) / 4, 256, 0, stream>>>(y, agg2, srcp, dstp, attr, E);
    } else {
        unsigned short* y = (unsigned short*)ybuf;
        gemm_mfma_kernel<32, unsigned short><<<ggrid, 256, 0, stream>>>(xb, w1h, w1l, y, agg1, b1, N);
        edge_kernel<unsigned short><<<(E + 3) / 4, 256, 0, stream>>>(y, agg1, srcp, dstp, attr, E);
        conv_bf16_kernel<true><<<(N * 64 + 255) / 256, 256, 0, stream>>>(agg1, h1b, N * 64);
        gemm_mfma_kernel<64, unsigned short><<<ggrid, 256, 0, stream>>>(h1b, w2h, w2l, y, agg2, b2, N);
        edge_kernel<unsigned short><<<(E + 3) / 4, 256, 0, stream>>>(y, agg2, srcp, dstp, attr, E);
    }

    final_kernel<<<(N + 3) / 4, 256, 0, stream>>>(agg2, fcw, fcb, (float*)d_out, N);
}

// Round 2
// 336.107 us; speedup vs baseline: 1.3671x; 1.3671x over previous
//
#include <hip/hip_runtime.h>
#include <stdint.h>

typedef __attribute__((ext_vector_type(8))) short short8;            // 8 bf16 (MFMA A/B frag)
typedef __attribute__((ext_vector_type(4))) float f32x4;             // MFMA C/D frag
typedef __attribute__((ext_vector_type(4))) unsigned short ushort4v; // 4 bf16 store

__device__ __forceinline__ unsigned short f2bf(float f) {
    unsigned int u = __float_as_uint(f);
    u = (u + 0x7FFFu + ((u >> 16) & 1u)) >> 16;  // RNE
    return (unsigned short)u;
}
__device__ __forceinline__ float bf2f(unsigned short h) {
    return __uint_as_float(((unsigned int)h) << 16);
}

// ---------------------------------------------------------------------------
// Pack W+root -> fragment-ordered bf16 hi/lo:
//   pk[(( (cb*4+c)*KCH + kc )*2 + h)*512 + lane*8 + j]
// holds element  col = cb*64 + c*16 + (lane&15),  k = kc*32 + (lane>>4)*8 + j
//   col < 1600: W[col>>6][k][col&63];  col >= 1600: root[k][col-1600]
// Split-W error feedback: hi = bf16(w), lo = bf16(w - f32(hi))
// ---------------------------------------------------------------------------
template<int KIN>
__global__ void pack_w_kernel(const float* __restrict__ W, const float* __restrict__ root,
                              unsigned short* __restrict__ pk) {
    constexpr int KCH = KIN / 32;
    int t = blockIdx.x * 256 + threadIdx.x;
    if (t >= 1664 * KIN) return;
    int j = t & 7;
    int r = t >> 3;
    int lane = r & 63; r >>= 6;            // r = (cb*4+c)*KCH + kc
    int kc = r % KCH;
    int cc = r / KCH;                      // cb*4 + c
    int col = cc * 16 + (lane & 15);
    int k   = kc * 32 + (lane >> 4) * 8 + j;
    float v = (col < 1600) ? W[((size_t)(col >> 6) * KIN + k) * 64 + (col & 63)]
                           : root[(size_t)k * 64 + (col - 1600)];
    unsigned short h = f2bf(v);
    size_t base = (size_t)r * 1024 + lane * 8 + j;
    pk[base]       = h;                    // hi slot
    pk[base + 512] = f2bf(v - bf2f(h));    // lo slot
}

// ---------------------------------------------------------------------------
// float -> bf16 convert (optional ReLU), vectorized 4-wide
// ---------------------------------------------------------------------------
template<bool RELU>
__global__ void conv_bf16_kernel(const float* __restrict__ in, unsigned short* __restrict__ out, int n4) {
    int t = blockIdx.x * 256 + threadIdx.x;
    if (t >= n4) return;
    float4 v = reinterpret_cast<const float4*>(in)[t];
    if (RELU) {
        v.x = fmaxf(v.x, 0.f); v.y = fmaxf(v.y, 0.f);
        v.z = fmaxf(v.z, 0.f); v.w = fmaxf(v.w, 0.f);
    }
    ushort4v o = { f2bf(v.x), f2bf(v.y), f2bf(v.z), f2bf(v.w) };
    reinterpret_cast<ushort4v*>(out)[t] = o;
}

// ---------------------------------------------------------------------------
// y[n, col] = Xb[n,:] @ (Whi+Wlo)[:, col]  (col<1600, bf16 out)
// agg[n,o]  = x@root + bias               (col>=1600, fp32 out)
// Block: 4 waves, tile M=256 x N=64. B slice (4 c-tiles x KCH x hi/lo) staged
// in LDS once per block (8-16KB, linear, conflict-free), reused by 4 waves x
// 4 m-frags. A frag = one contiguous 1-2KB wave load. 4 independent acc
// chains per (c) give MFMA ILP.
// mfma_f32_16x16x32_bf16: A[m=lane&15][k=(lane>>4)*8+j],
// B[k=(lane>>4)*8+j][n=lane&15], D col=lane&15, row=(lane>>4)*4+reg
// ---------------------------------------------------------------------------
template<int KIN>
__global__ __launch_bounds__(256) void gemm_mfma_kernel(
    const unsigned short* __restrict__ Xb,
    const unsigned short* __restrict__ pk,
    unsigned short* __restrict__ y, float* __restrict__ agg,
    const float* __restrict__ bias, int N)
{
    constexpr int KCH   = KIN / 32;
    constexpr int NFRAG = 4 * KCH * 2;         // 1KB frag units per col-block
    __shared__ unsigned short Blds[NFRAG * 512];

    const int lane = threadIdx.x & 63;
    const int wave = threadIdx.x >> 6;
    const int lrow = lane & 15;
    const int lch  = lane >> 4;
    const int cb   = blockIdx.x;               // col-block: 64 cols
    const int mbase = blockIdx.y * 256 + wave * 64;

    // ---- stage B slice (contiguous region of pk) into LDS ----
    {
        const short8* src = reinterpret_cast<const short8*>(pk + (size_t)cb * NFRAG * 512);
        short8* dst = reinterpret_cast<short8*>(Blds);
        #pragma unroll
        for (int p = 0; p < NFRAG / 4; p++) {
            int idx = p * 256 + threadIdx.x;   // 16B units, linear
            dst[idx] = src[idx];
        }
    }

    // ---- A fragments: 4 m-tiles, each a contiguous 16-row x KIN block ----
    short8 afrag[4][KCH];
    #pragma unroll
    for (int mt = 0; mt < 4; mt++) {
        int row = mbase + mt * 16 + lrow;
        if (row > N - 1) row = N - 1;          // clamp; stores are guarded
        const unsigned short* ap = Xb + (size_t)row * KIN + lch * 8;
        #pragma unroll
        for (int kc = 0; kc < KCH; kc++)
            afrag[mt][kc] = *reinterpret_cast<const short8*>(ap + kc * 32);
    }

    __syncthreads();

    f32x4 acc[4][4];                           // [c][mt]
    #pragma unroll
    for (int c = 0; c < 4; c++)
        #pragma unroll
        for (int mt = 0; mt < 4; mt++)
            acc[c][mt] = (f32x4){0.f, 0.f, 0.f, 0.f};

    #pragma unroll
    for (int c = 0; c < 4; c++) {
        short8 bh[KCH], bl[KCH];
        #pragma unroll
        for (int kc = 0; kc < KCH; kc++) {
            bh[kc] = *reinterpret_cast<const short8*>(&Blds[((c * KCH + kc) * 2 + 0) * 512 + lane * 8]);
            bl[kc] = *reinterpret_cast<const short8*>(&Blds[((c * KCH + kc) * 2 + 1) * 512 + lane * 8]);
        }
        #pragma unroll
        for (int mt = 0; mt < 4; mt++) {
            #pragma unroll
            for (int kc = 0; kc < KCH; kc++) {
                acc[c][mt] = __builtin_amdgcn_mfma_f32_16x16x32_bf16(afrag[mt][kc], bh[kc], acc[c][mt], 0, 0, 0);
                acc[c][mt] = __builtin_amdgcn_mfma_f32_16x16x32_bf16(afrag[mt][kc], bl[kc], acc[c][mt], 0, 0, 0);
            }
        }
    }

    // ---- epilogue ----
    #pragma unroll
    for (int c = 0; c < 4; c++) {
        int colb = cb * 64 + c * 16;
        int col  = colb + lrow;
        if (colb < 1600) {
            #pragma unroll
            for (int mt = 0; mt < 4; mt++) {
                int mb = mbase + mt * 16 + lch * 4;
                #pragma unroll
                for (int r = 0; r < 4; r++) {
                    int m = mb + r;
                    if (m < N) y[(size_t)m * 1600 + col] = f2bf(acc[c][mt][r]);
                }
            }
        } else {
            int o = col - 1600;
            float bv = bias[o];
            #pragma unroll
            for (int mt = 0; mt < 4; mt++) {
                int mb = mbase + mt * 16 + lch * 4;
                #pragma unroll
                for (int r = 0; r < 4; r++) {
                    int m = mb + r;
                    if (m < N) agg[(size_t)m * 64 + o] = acc[c][mt][r] + bv;
                }
            }
        }
    }
}

// ---------------------------------------------------------------------------
// Per-edge gather + basis-weighted sum + atomic scatter (y is bf16).
// 1 wave per edge; lane = output channel. 4 contiguous 128B row gathers,
// one coalesced 256B atomicAdd row per edge.
// ---------------------------------------------------------------------------
__global__ __launch_bounds__(256) void edge_kernel(
    const unsigned short* __restrict__ y, float* __restrict__ agg,
    const int* __restrict__ src, const int* __restrict__ dst,
    const float* __restrict__ attr, int E)
{
    int e = blockIdx.x * 4 + (threadIdx.x >> 6);
    if (e >= E) return;
    int lane = threadIdx.x & 63;
    float2 av = reinterpret_cast<const float2*>(attr)[e];
    float v0 = av.x * 4.f, v1 = av.y * 4.f;
    float fl0 = floorf(v0), fl1 = floorf(v1);
    float f0 = v0 - fl0, f1 = v1 - fl1;
    int i0 = (int)fl0, i1 = (int)fl1;
    int s = src[e], d = dst[e];
    const unsigned short* yb = y + (size_t)s * 1600 + lane;
    float msg = 0.f;
    #pragma unroll
    for (int t = 0; t < 4; t++) {
        int b0 = t & 1, b1 = t >> 1;
        float wx = b0 ? f0 : 1.f - f0;
        float wy = b1 ? f1 : 1.f - f1;
        int id0 = i0 + b0; if (id0 > 4) id0 = 4;
        int id1 = i1 + b1; if (id1 > 4) id1 = 4;
        msg += wx * wy * bf2f(yb[(id0 + 5 * id1) * 64]);
    }
    atomicAdd(agg + (size_t)d * 64 + lane, msg);
}

// ---------------------------------------------------------------------------
// out[n,:3] = relu(agg2[n,:]) @ fc_w + fc_b   (wave per node, shuffle reduce)
// ---------------------------------------------------------------------------
__global__ __launch_bounds__(256) void final_kernel(
    const float* __restrict__ agg2, const float* __restrict__ fcw,
    const float* __restrict__ fcb, float* __restrict__ out, int N)
{
    int n = blockIdx.x * 4 + (threadIdx.x >> 6);
    if (n >= N) return;
    int lane = threadIdx.x & 63;
    float a = fmaxf(agg2[(size_t)n * 64 + lane], 0.f);
    float p0 = a * fcw[lane * 3 + 0];
    float p1 = a * fcw[lane * 3 + 1];
    float p2 = a * fcw[lane * 3 + 2];
    #pragma unroll
    for (int off = 32; off; off >>= 1) {
        p0 += __shfl_xor(p0, off);
        p1 += __shfl_xor(p1, off);
        p2 += __shfl_xor(p2, off);
    }
    if (lane == 0) {
        out[(size_t)n * 3 + 0] = p0 + fcb[0];
        out[(size_t)n * 3 + 1] = p1 + fcb[1];
        out[(size_t)n * 3 + 2] = p2 + fcb[2];
    }
}

// ---------------------------------------------------------------------------
extern "C" void kernel_launch(void* const* d_in, const int* in_sizes, int n_in,
                              void* d_out, int out_size, void* d_ws, size_t ws_size,
                              hipStream_t stream)
{
    const float* x     = (const float*)d_in[0];
    const int*   ei    = (const int*)  d_in[1];
    const float* attr  = (const float*)d_in[2];
    const float* W1    = (const float*)d_in[3];
    const float* root1 = (const float*)d_in[4];
    const float* b1    = (const float*)d_in[5];
    const float* W2    = (const float*)d_in[6];
    const float* root2 = (const float*)d_in[7];
    const float* b2    = (const float*)d_in[8];
    const float* fcw   = (const float*)d_in[9];
    const float* fcb   = (const float*)d_in[10];

    const int N = in_sizes[0] / 32;
    const int E = in_sizes[1] / 2;
    const int* srcp = ei;
    const int* dstp = ei + E;

    char* wsp = (char*)d_ws;
    auto alloc = [&](size_t bytes) -> char* {
        char* p = wsp;
        wsp += (bytes + 255) & ~(size_t)255;
        return p;
    };
    float*          agg1 = (float*)alloc((size_t)N * 64 * 4);
    float*          agg2 = (float*)alloc((size_t)N * 64 * 4);
    unsigned short* xb   = (unsigned short*)alloc((size_t)N * 32 * 2);
    unsigned short* h1b  = (unsigned short*)alloc((size_t)N * 64 * 2);
    unsigned short* pk1  = (unsigned short*)alloc((size_t)1664 * 32 * 2 * 2);
    unsigned short* pk2  = (unsigned short*)alloc((size_t)1664 * 64 * 2 * 2);
    unsigned short* y    = (unsigned short*)alloc((size_t)N * 1600 * 2);

    const int Mtiles = (N + 255) / 256;
    dim3 ggrid(26, Mtiles);

    pack_w_kernel<32><<<(1664 * 32 + 255) / 256, 256, 0, stream>>>(W1, root1, pk1);
    pack_w_kernel<64><<<(1664 * 64 + 255) / 256, 256, 0, stream>>>(W2, root2, pk2);
    conv_bf16_kernel<false><<<(N * 8 + 255) / 256, 256, 0, stream>>>(x, xb, N * 8);

    gemm_mfma_kernel<32><<<ggrid, 256, 0, stream>>>(xb, pk1, y, agg1, b1, N);
    edge_kernel<<<(E + 3) / 4, 256, 0, stream>>>(y, agg1, srcp, dstp, attr, E);
    conv_bf16_kernel<true><<<(N * 16 + 255) / 256, 256, 0, stream>>>(agg1, h1b, N * 16);
    gemm_mfma_kernel<64><<<ggrid, 256, 0, stream>>>(h1b, pk2, y, agg2, b2, N);
    edge_kernel<<<(E + 3) / 4, 256, 0, stream>>>(y, agg2, srcp, dstp, attr, E);

    final_kernel<<<(N + 3) / 4, 256, 0, stream>>>(agg2, fcw, fcb, (float*)d_out, N);
}

// Round 3
// 268.601 us; speedup vs baseline: 1.7107x; 1.2513x over previous
//
#include <hip/hip_runtime.h>
#include <stdint.h>

typedef __attribute__((ext_vector_type(8))) short short8;            // 8 bf16 (MFMA A/B frag)
typedef __attribute__((ext_vector_type(4))) float f32x4;             // MFMA C/D frag
typedef __attribute__((ext_vector_type(4))) unsigned short ushort4v;

__device__ __forceinline__ unsigned short f2bf(float f) {
    unsigned int u = __float_as_uint(f);
    u = (u + 0x7FFFu + ((u >> 16) & 1u)) >> 16;  // RNE
    return (unsigned short)u;
}
__device__ __forceinline__ float bf2f(unsigned short h) {
    return __uint_as_float(((unsigned int)h) << 16);
}
__device__ __forceinline__ int cell_of(float ax, float ay) {
    int c0 = (int)floorf(ax * 4.f); c0 = min(max(c0, 0), 3);
    int c1 = (int)floorf(ay * 4.f); c1 = min(max(c1, 0), 3);
    return c0 + 4 * c1;
}

// ---------------------------------------------------------------------------
// Bucketing: hist -> scan -> ballot-ranked scatter (order within bucket free)
// ---------------------------------------------------------------------------
__global__ __launch_bounds__(256) void hist_kernel(const float* __restrict__ attr,
                                                   int* __restrict__ hist, int E) {
    __shared__ int wcnt[4][16];
    int e = blockIdx.x * 256 + threadIdx.x;
    int lane = threadIdx.x & 63, wave = threadIdx.x >> 6;
    int cell = -1;
    if (e < E) {
        float2 a = reinterpret_cast<const float2*>(attr)[e];
        cell = cell_of(a.x, a.y);
    }
    #pragma unroll
    for (int c = 0; c < 16; c++) {
        unsigned long long m = __ballot(cell == c);
        if (lane == 0) wcnt[wave][c] = __popcll(m);
    }
    __syncthreads();
    if (threadIdx.x < 16) {
        int c = threadIdx.x;
        int tot = wcnt[0][c] + wcnt[1][c] + wcnt[2][c] + wcnt[3][c];
        if (tot) atomicAdd(&hist[c], tot);
    }
}

__global__ void scan_kernel(const int* __restrict__ hist, int* __restrict__ off_e,
                            int* __restrict__ off_b, int* __restrict__ cursor) {
    if (threadIdx.x == 0 && blockIdx.x == 0) {
        int se = 0, sb = 0;
        for (int c = 0; c < 16; c++) {
            off_e[c] = se; off_b[c] = sb; cursor[c] = se;
            se += hist[c]; sb += (hist[c] + 63) >> 6;
        }
        off_e[16] = se; off_b[16] = sb;
    }
}

__global__ __launch_bounds__(256) void scatter_kernel(const float* __restrict__ attr,
                                                      int* __restrict__ bucket,
                                                      int* __restrict__ cursor, int E) {
    __shared__ int wcnt[4][16];
    __shared__ int wbase[4][16];
    int e = blockIdx.x * 256 + threadIdx.x;
    int lane = threadIdx.x & 63, wave = threadIdx.x >> 6;
    int cell = -1;
    if (e < E) {
        float2 a = reinterpret_cast<const float2*>(attr)[e];
        cell = cell_of(a.x, a.y);
    }
    int myrank = 0;
    #pragma unroll
    for (int c = 0; c < 16; c++) {
        unsigned long long m = __ballot(cell == c);
        if (cell == c) myrank = __popcll(m & ((1ull << lane) - 1ull));
        if (lane == 0) wcnt[wave][c] = __popcll(m);
    }
    __syncthreads();
    if (threadIdx.x < 16) {
        int c = threadIdx.x;
        int t0 = wcnt[0][c], t1 = wcnt[1][c], t2 = wcnt[2][c], t3 = wcnt[3][c];
        int tot = t0 + t1 + t2 + t3;
        int g = tot ? atomicAdd(&cursor[c], tot) : 0;
        wbase[0][c] = g;
        wbase[1][c] = g + t0;
        wbase[2][c] = g + t0 + t1;
        wbase[3][c] = g + t0 + t1 + t2;
    }
    __syncthreads();
    if (e < E) bucket[wbase[wave][cell] + myrank] = e;
}

// ---------------------------------------------------------------------------
// Pack per-cell concatenated W (4 corners) into MFMA-frag order, single bf16:
//   pkc[((cell*4 + c)*KCH + kc)*512 + lane*8 + j] =
//     W[kidx(cell, t)][i][c*16 + (lane&15)],  k = kc*32+(lane>>4)*8+j,
//     t = k/KIN, i = k%KIN, kidx = min(c0+(t&1),4) + 5*min(c1+(t>>1),4)
// ---------------------------------------------------------------------------
template<int KIN>
__global__ void pack_cell_kernel(const float* __restrict__ W, unsigned short* __restrict__ pkc) {
    constexpr int KCH = KIN / 8;  // 4*KIN/32
    int u = blockIdx.x * 256 + threadIdx.x;
    if (u >= 16 * 4 * KCH * 512) return;
    int low9 = u & 511;
    int grp  = u >> 9;
    int kc = grp % KCH; grp /= KCH;
    int c  = grp & 3;
    int cell = grp >> 2;
    int lane = low9 >> 3, j = low9 & 7;
    int k = kc * 32 + (lane >> 4) * 8 + j;
    int t = k / KIN, i = k % KIN;
    int k0 = (cell & 3) + (t & 1);  if (k0 > 4) k0 = 4;
    int k1 = (cell >> 2) + (t >> 1); if (k1 > 4) k1 = 4;
    float val = W[((size_t)(k0 + 5 * k1) * KIN + i) * 64 + (c * 16 + (lane & 15))];
    pkc[u] = f2bf(val);
}

// ---------------------------------------------------------------------------
// Pack root -> frag order with hi/lo split (error feedback)
// ---------------------------------------------------------------------------
template<int KIN>
__global__ void pack_root_kernel(const float* __restrict__ root, unsigned short* __restrict__ pkr) {
    constexpr int KCHr = KIN / 32;
    int u = blockIdx.x * 256 + threadIdx.x;
    if (u >= 4 * KCHr * 512) return;
    int low9 = u & 511;
    int grp  = u >> 9;               // c*KCHr + kc
    int lane = low9 >> 3, j = low9 & 7;
    int kc = grp % KCHr, c = grp / KCHr;
    int k = kc * 32 + (lane >> 4) * 8 + j;
    int o = c * 16 + (lane & 15);
    float v = root[(size_t)k * 64 + o];
    unsigned short h = f2bf(v);
    pkr[(size_t)(grp * 2) * 512 + low9]       = h;
    pkr[(size_t)(grp * 2 + 1) * 512 + low9]   = f2bf(v - bf2f(h));
}

// ---------------------------------------------------------------------------
// float -> bf16 (optional ReLU), 4-wide
// ---------------------------------------------------------------------------
template<bool RELU>
__global__ void conv_bf16_kernel(const float* __restrict__ in, unsigned short* __restrict__ out, int n4) {
    int t = blockIdx.x * 256 + threadIdx.x;
    if (t >= n4) return;
    float4 v = reinterpret_cast<const float4*>(in)[t];
    if (RELU) {
        v.x = fmaxf(v.x, 0.f); v.y = fmaxf(v.y, 0.f);
        v.z = fmaxf(v.z, 0.f); v.w = fmaxf(v.w, 0.f);
    }
    ushort4v o = { f2bf(v.x), f2bf(v.y), f2bf(v.z), f2bf(v.w) };
    reinterpret_cast<ushort4v*>(out)[t] = o;
}

// ---------------------------------------------------------------------------
// agg[n,:] = x @ (root_hi + root_lo) + bias   (initializes agg)
// ---------------------------------------------------------------------------
template<int KIN>
__global__ __launch_bounds__(256) void root_gemm_kernel(
    const unsigned short* __restrict__ Xb, const unsigned short* __restrict__ pkr,
    float* __restrict__ agg, const float* __restrict__ bias, int N)
{
    constexpr int KCHr = KIN / 32;
    const int lane = threadIdx.x & 63;
    const int wave = threadIdx.x >> 6;
    const int lrow = lane & 15, lch = lane >> 4;
    const int mbase = blockIdx.x * 64 + wave * 16;

    short8 afrag[KCHr];
    {
        int row = mbase + lrow;
        if (row > N - 1) row = N - 1;
        const unsigned short* ap = Xb + (size_t)row * KIN + lch * 8;
        #pragma unroll
        for (int kc = 0; kc < KCHr; kc++)
            afrag[kc] = *reinterpret_cast<const short8*>(ap + kc * 32);
    }
    f32x4 acc[4];
    #pragma unroll
    for (int c = 0; c < 4; c++) acc[c] = (f32x4){0.f, 0.f, 0.f, 0.f};
    #pragma unroll
    for (int c = 0; c < 4; c++) {
        #pragma unroll
        for (int kc = 0; kc < KCHr; kc++) {
            short8 bh = *reinterpret_cast<const short8*>(pkr + ((size_t)(c * KCHr + kc) * 2    ) * 512 + lane * 8);
            short8 bl = *reinterpret_cast<const short8*>(pkr + ((size_t)(c * KCHr + kc) * 2 + 1) * 512 + lane * 8);
            acc[c] = __builtin_amdgcn_mfma_f32_16x16x32_bf16(afrag[kc], bh, acc[c], 0, 0, 0);
            acc[c] = __builtin_amdgcn_mfma_f32_16x16x32_bf16(afrag[kc], bl, acc[c], 0, 0, 0);
        }
    }
    #pragma unroll
    for (int c = 0; c < 4; c++) {
        int o = c * 16 + lrow;
        float bv = bias[o];
        #pragma unroll
        for (int r = 0; r < 4; r++) {
            int m = mbase + lch * 4 + r;
            if (m < N) agg[(size_t)m * 64 + o] = acc[c][r] + bv;
        }
    }
}

// ---------------------------------------------------------------------------
// Cell-bucketed edge GEMM:
//   per 16-edge tile: G[t] = X[src rows] @ W[k_t(cell)]  (4 MFMA chains, fp32)
//   msg = sum_t w_t(edge) * G[t]  (per-row weights via shfl; D row = edge)
//   atomicAdd into agg[dst]
// Block = 4 waves x 16 edges = 64 edges; Wcat[cell] staged in LDS (16/32KB).
// ---------------------------------------------------------------------------
template<int KIN>
__global__ __launch_bounds__(256) void edge_gemm_kernel(
    const unsigned short* __restrict__ Xb,
    const unsigned short* __restrict__ pkc,
    float* __restrict__ agg,
    const int* __restrict__ src, const int* __restrict__ dst,
    const float* __restrict__ attr, const int* __restrict__ bucket,
    const int* __restrict__ off_e, const int* __restrict__ off_b)
{
    constexpr int KCHr = KIN / 32;
    constexpr int KCH  = 4 * KCHr;
    __shared__ unsigned short Blds[4 * KCH * 512];

    const int b = blockIdx.x;
    if (b >= off_b[16]) return;
    int cell = 0;
    #pragma unroll
    for (int c = 1; c < 16; c++) cell += (b >= off_b[c]);
    const int tile = b - off_b[cell];

    {   // stage Wcat[cell] -> LDS (linear, conflict-free)
        const short8* sp = reinterpret_cast<const short8*>(pkc + (size_t)cell * (4 * KCH * 512));
        short8* dp = reinterpret_cast<short8*>(Blds);
        #pragma unroll
        for (int p = 0; p < (4 * KCH * 512 / 8) / 256; p++)
            dp[p * 256 + threadIdx.x] = sp[p * 256 + threadIdx.x];
    }

    const int lane = threadIdx.x & 63;
    const int wave = threadIdx.x >> 6;
    const int lrow = lane & 15, lch = lane >> 4;

    const int ebeg = off_e[cell];
    const int eend = off_e[cell + 1];
    const int eslot = ebeg + (tile * 4 + wave) * 16 + lrow;
    const bool valid = eslot < eend;

    int eid = 0, s = 0;
    float ax = 0.f, ay = 0.f;
    if (valid) {
        eid = bucket[eslot];
        s = src[eid];
        float2 a = reinterpret_cast<const float2*>(attr)[eid];
        ax = a.x; ay = a.y;
    }
    const float f0 = ax * 4.f - (float)(cell & 3);
    const float f1 = ay * 4.f - (float)(cell >> 2);
    float w[4] = { (1.f - f0) * (1.f - f1), f0 * (1.f - f1),
                   (1.f - f0) * f1,         f0 * f1 };

    short8 xfrag[KCHr];
    {
        const unsigned short* xp = Xb + (size_t)s * KIN + lch * 8;
        #pragma unroll
        for (int kcr = 0; kcr < KCHr; kcr++)
            xfrag[kcr] = *reinterpret_cast<const short8*>(xp + kcr * 32);
    }

    __syncthreads();

    f32x4 accT[4][4];  // [t][c]
    #pragma unroll
    for (int t = 0; t < 4; t++)
        #pragma unroll
        for (int c = 0; c < 4; c++)
            accT[t][c] = (f32x4){0.f, 0.f, 0.f, 0.f};

    #pragma unroll
    for (int t = 0; t < 4; t++) {
        #pragma unroll
        for (int kcr = 0; kcr < KCHr; kcr++) {
            #pragma unroll
            for (int c = 0; c < 4; c++) {
                short8 bf = *reinterpret_cast<const short8*>(
                    &Blds[(size_t)((c * KCH) + (t * KCHr + kcr)) * 512 + lane * 8]);
                accT[t][c] = __builtin_amdgcn_mfma_f32_16x16x32_bf16(xfrag[kcr], bf, accT[t][c], 0, 0, 0);
            }
        }
    }

    // per-row basis weights + dst (D layout: row = lch*4+r = edge-in-tile)
    float wr[4][4];
    #pragma unroll
    for (int t = 0; t < 4; t++)
        #pragma unroll
        for (int r = 0; r < 4; r++)
            wr[t][r] = __shfl(w[t], lch * 4 + r);
    int dv[4], vv[4];
    #pragma unroll
    for (int r = 0; r < 4; r++) {
        vv[r] = __shfl((int)valid, lch * 4 + r);
        int er = __shfl(eid, lch * 4 + r);
        dv[r] = dst[er];
    }
    #pragma unroll
    for (int c = 0; c < 4; c++) {
        const int o = c * 16 + lrow;
        #pragma unroll
        for (int r = 0; r < 4; r++) {
            if (vv[r]) {
                float m = wr[0][r] * accT[0][c][r] + wr[1][r] * accT[1][c][r]
                        + wr[2][r] * accT[2][c][r] + wr[3][r] * accT[3][c][r];
                atomicAdd(agg + (size_t)dv[r] * 64 + o, m);
            }
        }
    }
}

// ---------------------------------------------------------------------------
// out[n,:3] = relu(agg2[n,:]) @ fc_w + fc_b
// ---------------------------------------------------------------------------
__global__ __launch_bounds__(256) void final_kernel(
    const float* __restrict__ agg2, const float* __restrict__ fcw,
    const float* __restrict__ fcb, float* __restrict__ out, int N)
{
    int n = blockIdx.x * 4 + (threadIdx.x >> 6);
    if (n >= N) return;
    int lane = threadIdx.x & 63;
    float a = fmaxf(agg2[(size_t)n * 64 + lane], 0.f);
    float p0 = a * fcw[lane * 3 + 0];
    float p1 = a * fcw[lane * 3 + 1];
    float p2 = a * fcw[lane * 3 + 2];
    #pragma unroll
    for (int off = 32; off; off >>= 1) {
        p0 += __shfl_xor(p0, off);
        p1 += __shfl_xor(p1, off);
        p2 += __shfl_xor(p2, off);
    }
    if (lane == 0) {
        out[(size_t)n * 3 + 0] = p0 + fcb[0];
        out[(size_t)n * 3 + 1] = p1 + fcb[1];
        out[(size_t)n * 3 + 2] = p2 + fcb[2];
    }
}

// ---------------------------------------------------------------------------
extern "C" void kernel_launch(void* const* d_in, const int* in_sizes, int n_in,
                              void* d_out, int out_size, void* d_ws, size_t ws_size,
                              hipStream_t stream)
{
    const float* x     = (const float*)d_in[0];
    const int*   ei    = (const int*)  d_in[1];
    const float* attr  = (const float*)d_in[2];
    const float* W1    = (const float*)d_in[3];
    const float* root1 = (const float*)d_in[4];
    const float* b1    = (const float*)d_in[5];
    const float* W2    = (const float*)d_in[6];
    const float* root2 = (const float*)d_in[7];
    const float* b2    = (const float*)d_in[8];
    const float* fcw   = (const float*)d_in[9];
    const float* fcb   = (const float*)d_in[10];

    const int N = in_sizes[0] / 32;
    const int E = in_sizes[1] / 2;
    const int* srcp = ei;
    const int* dstp = ei + E;

    char* wsp = (char*)d_ws;
    auto alloc = [&](size_t bytes) -> char* {
        char* p = wsp;
        wsp += (bytes + 255) & ~(size_t)255;
        return p;
    };
    float*          agg1   = (float*)alloc((size_t)N * 64 * 4);
    float*          agg2   = (float*)alloc((size_t)N * 64 * 4);
    unsigned short* xb     = (unsigned short*)alloc((size_t)N * 32 * 2);
    unsigned short* h1b    = (unsigned short*)alloc((size_t)N * 64 * 2);
    unsigned short* pkr1   = (unsigned short*)alloc((size_t)4 * 1 * 2 * 512 * 2);
    unsigned short* pkr2   = (unsigned short*)alloc((size_t)4 * 2 * 2 * 512 * 2);
    unsigned short* pkc1   = (unsigned short*)alloc((size_t)16 * 4 * 4 * 512 * 2);
    unsigned short* pkc2   = (unsigned short*)alloc((size_t)16 * 4 * 8 * 512 * 2);
    int*            bucket = (int*)alloc((size_t)E * 4);
    int*            hist   = (int*)alloc(16 * 4);
    int*            off_e  = (int*)alloc(17 * 4);
    int*            off_b  = (int*)alloc(17 * 4);
    int*            cursor = (int*)alloc(16 * 4);

    hipMemsetAsync(hist, 0, 16 * 4, stream);

    const int EB = (E + 255) / 256;
    hist_kernel<<<EB, 256, 0, stream>>>(attr, hist, E);
    scan_kernel<<<1, 64, 0, stream>>>(hist, off_e, off_b, cursor);
    scatter_kernel<<<EB, 256, 0, stream>>>(attr, bucket, cursor, E);

    pack_cell_kernel<32><<<(16 * 4 * 4 * 512) / 256, 256, 0, stream>>>(W1, pkc1);
    pack_cell_kernel<64><<<(16 * 4 * 8 * 512) / 256, 256, 0, stream>>>(W2, pkc2);
    pack_root_kernel<32><<<(4 * 1 * 512 + 255) / 256, 256, 0, stream>>>(root1, pkr1);
    pack_root_kernel<64><<<(4 * 2 * 512 + 255) / 256, 256, 0, stream>>>(root2, pkr2);

    conv_bf16_kernel<false><<<(N * 8 + 255) / 256, 256, 0, stream>>>(x, xb, N * 8);

    const int egrid = (E + 63) / 64 + 16;

    root_gemm_kernel<32><<<(N + 63) / 64, 256, 0, stream>>>(xb, pkr1, agg1, b1, N);
    edge_gemm_kernel<32><<<egrid, 256, 0, stream>>>(xb, pkc1, agg1, srcp, dstp, attr, bucket, off_e, off_b);

    conv_bf16_kernel<true><<<(N * 16 + 255) / 256, 256, 0, stream>>>(agg1, h1b, N * 16);

    root_gemm_kernel<64><<<(N + 63) / 64, 256, 0, stream>>>(h1b, pkr2, agg2, b2, N);
    edge_gemm_kernel<64><<<egrid, 256, 0, stream>>>(h1b, pkc2, agg2, srcp, dstp, attr, bucket, off_e, off_b);

    final_kernel<<<(N + 3) / 4, 256, 0, stream>>>(agg2, fcw, fcb, (float*)d_out, N);
}